// Round 8
// baseline (576.855 us; speedup 1.0000x reference)
//
#include <hip/hip_runtime.h>

#define BN_EPS 1e-5f

typedef __attribute__((ext_vector_type(8))) short bf16x8;
typedef __attribute__((ext_vector_type(4))) float f32x4;

__device__ __forceinline__ float bf2f(unsigned short u) {
  return __uint_as_float(((unsigned int)u) << 16);
}
__device__ __forceinline__ unsigned short f2bf(float f) {
  unsigned int u = __float_as_uint(f);
  u = u + 0x7FFFu + ((u >> 16) & 1u);   // round-to-nearest-even
  return (unsigned short)(u >> 16);
}

// ---------------- graph structure ----------------

__global__ __launch_bounds__(256) void count_boundary(const int* __restrict__ dst, int E,
                                                      int* __restrict__ counts,
                                                      const int* __restrict__ batch, int N,
                                                      unsigned int* __restrict__ gstart) {
  int e = blockIdx.x * 256 + threadIdx.x;
  if (e < E) atomicAdd(&counts[dst[e]], 1);
  if (e < N) {
    if (e == 0 || batch[e] != batch[e - 1]) atomicMin(&gstart[batch[e]], (unsigned int)e);
  }
}

__global__ __launch_bounds__(256) void scan1(const int* __restrict__ counts, int N,
                                             int* __restrict__ offs, int* __restrict__ blkSum,
                                             float* __restrict__ dinv) {
  __shared__ int sd[256];
  int t = threadIdx.x;
  int i0 = blockIdx.x * 1024 + t * 4;
  int v0 = (i0 + 0 < N) ? counts[i0 + 0] : 0;
  int v1 = (i0 + 1 < N) ? counts[i0 + 1] : 0;
  int v2 = (i0 + 2 < N) ? counts[i0 + 2] : 0;
  int v3 = (i0 + 3 < N) ? counts[i0 + 3] : 0;
  if (i0 + 0 < N) dinv[i0 + 0] = rsqrtf((float)(v0 + 1));
  if (i0 + 1 < N) dinv[i0 + 1] = rsqrtf((float)(v1 + 1));
  if (i0 + 2 < N) dinv[i0 + 2] = rsqrtf((float)(v2 + 1));
  if (i0 + 3 < N) dinv[i0 + 3] = rsqrtf((float)(v3 + 1));
  int tot = v0 + v1 + v2 + v3;
  sd[t] = tot;
  __syncthreads();
  for (int off = 1; off < 256; off <<= 1) {
    int x = (t >= off) ? sd[t - off] : 0;
    __syncthreads();
    sd[t] += x;
    __syncthreads();
  }
  int excl = sd[t] - tot;
  if (i0 + 0 < N) offs[i0 + 0] = excl;
  if (i0 + 1 < N) offs[i0 + 1] = excl + v0;
  if (i0 + 2 < N) offs[i0 + 2] = excl + v0 + v1;
  if (i0 + 3 < N) offs[i0 + 3] = excl + v0 + v1 + v2;
  if (t == 255) blkSum[blockIdx.x] = sd[255];
}

__global__ void scan2_fix(const int* __restrict__ blkSum, int nb, int* __restrict__ blkOff,
                          int* __restrict__ offs, int N,
                          unsigned int* __restrict__ gstart, int G) {
  if (blockIdx.x != 0) return;
  if (threadIdx.x == 0) {
    int run = 0;
    for (int b = 0; b < nb; ++b) { blkOff[b] = run; run += blkSum[b]; }
    offs[N] = run;
  } else if (threadIdx.x == 1) {
    gstart[G] = (unsigned int)N;
    for (int g = G - 1; g >= 0; --g)
      if (gstart[g] == 0xFFFFFFFFu) gstart[g] = gstart[g + 1];
  }
}

__global__ __launch_bounds__(1024) void scan3(int* __restrict__ offs, int N,
                                              const int* __restrict__ blkOff) {
  int i = blockIdx.x * 1024 + threadIdx.x;
  if (i < N) offs[i] += blkOff[blockIdx.x];
}

// ---------------- fill CSR + dtype conversions + pad zeroing (one dispatch) ----------------

__global__ __launch_bounds__(256) void fill_cvt(const int* __restrict__ src,
                                                const int* __restrict__ dst, int E,
                                                const int* __restrict__ offs,
                                                int* __restrict__ cursor,
                                                const float* __restrict__ dinv,
                                                int2* __restrict__ csr,
                                                const float* __restrict__ x,
                                                unsigned short* __restrict__ xb, int nx4,
                                                const float* __restrict__ W0,
                                                unsigned short* __restrict__ Wt0,
                                                const float* __restrict__ W1,
                                                unsigned short* __restrict__ Wt1,
                                                const float* __restrict__ W2,
                                                unsigned short* __restrict__ Wt2,
                                                unsigned short* __restrict__ pad128, int npad128_8,
                                                unsigned short* __restrict__ pad256, int npad256_8) {
  long long idx = (long long)blockIdx.x * 256 + threadIdx.x;
  if (idx < E) {
    int e = (int)idx;
    int s = src[e], d = dst[e];
    int pos = offs[d] + atomicAdd(&cursor[d], 1);
    csr[pos] = make_int2(s, __float_as_int(dinv[s] * dinv[d]));
    return;
  }
  idx -= E;
  if (idx < nx4) {
    float4 v = ((const float4*)x)[idx];
    unsigned int lo = (unsigned int)f2bf(v.x) | ((unsigned int)f2bf(v.y) << 16);
    unsigned int hi = (unsigned int)f2bf(v.z) | ((unsigned int)f2bf(v.w) << 16);
    ((uint2*)xb)[idx] = make_uint2(lo, hi);
    return;
  }
  idx -= nx4;
  if (idx < 128 * 256) {
    int k = (int)(idx >> 8), n = (int)(idx & 255);
    Wt0[n * 128 + k] = f2bf(W0[k * 256 + n]);
    return;
  }
  idx -= 128 * 256;
  if (idx < 256 * 256) {
    int k = (int)(idx >> 8), n = (int)(idx & 255);
    Wt1[n * 256 + k] = f2bf(W1[k * 256 + n]);
    return;
  }
  idx -= 256 * 256;
  if (idx < 256 * 256) {
    int k = (int)(idx >> 8), n = (int)(idx & 255);
    Wt2[n * 256 + k] = f2bf(W2[k * 256 + n]);
    return;
  }
  idx -= 256 * 256;
  if (idx < npad128_8) { ((uint4*)pad128)[idx] = make_uint4(0, 0, 0, 0); return; }
  idx -= npad128_8;
  if (idx < npad256_8) { ((uint4*)pad256)[idx] = make_uint4(0, 0, 0, 0); return; }
}

// ---------------- aggregation (gather, CSR by dst), one wave per node ----------------
// 8-edge unroll, 4 accumulator chains, 8 gathers in flight.

__device__ __forceinline__ void acc256(uint2 v, float co, float4 sc, float4 sh,
                                       float& ax, float& ay, float& az, float& aw) {
  float fx = fmaxf(bf2f((unsigned short)(v.x & 0xffff)) * sc.x + sh.x, 0.f);
  float fy = fmaxf(bf2f((unsigned short)(v.x >> 16)) * sc.y + sh.y, 0.f);
  float fz = fmaxf(bf2f((unsigned short)(v.y & 0xffff)) * sc.z + sh.z, 0.f);
  float fw = fmaxf(bf2f((unsigned short)(v.y >> 16)) * sc.w + sh.w, 0.f);
  ax += co * fx; ay += co * fy; az += co * fz; aw += co * fw;
}

__global__ __launch_bounds__(256) void agg256_bf(const unsigned short* __restrict__ h,
                                                 const int* __restrict__ offs,
                                                 const int2* __restrict__ csr,
                                                 const float* __restrict__ dinv,
                                                 const float* __restrict__ sums,
                                                 const float* __restrict__ sumsq,
                                                 const float* __restrict__ gamma,
                                                 const float* __restrict__ beta,
                                                 float invN,
                                                 unsigned short* __restrict__ out, int N) {
  __shared__ float s_sc[256], s_sh[256];
  {
    int c = threadIdx.x;
    float mean = sums[c] * invN;
    float var = sumsq[c] * invN - mean * mean;
    float scv = gamma[c] * rsqrtf(var + BN_EPS);
    s_sc[c] = scv;
    s_sh[c] = beta[c] - mean * scv;
  }
  __syncthreads();
  int n = (blockIdx.x * 256 + threadIdx.x) >> 6;
  int lane = threadIdx.x & 63;
  if (n >= N) return;
  float4 sc = *(const float4*)&s_sc[lane * 4];
  float4 sh = *(const float4*)&s_sh[lane * 4];
  float di = dinv[n];
  float self = di * di;
  float ax0 = 0.f, ay0 = 0.f, az0 = 0.f, aw0 = 0.f;
  float ax1 = 0.f, ay1 = 0.f, az1 = 0.f, aw1 = 0.f;
  float ax2 = 0.f, ay2 = 0.f, az2 = 0.f, aw2 = 0.f;
  float ax3 = 0.f, ay3 = 0.f, az3 = 0.f, aw3 = 0.f;
  {
    uint2 v = *((const uint2*)(h + (size_t)n * 256) + lane);
    acc256(v, self, sc, sh, ax0, ay0, az0, aw0);
  }
  int e0 = offs[n], e1 = offs[n + 1];
  for (int eb = e0; eb < e1; eb += 64) {
    int k = min(64, e1 - eb);
    int2 me = make_int2(0, 0);
    if (lane < k) me = csr[eb + lane];
    int i = 0;
    for (; i + 8 <= k; i += 8) {
      int s0 = __shfl(me.x, i),     s1 = __shfl(me.x, i + 1);
      int s2 = __shfl(me.x, i + 2), s3 = __shfl(me.x, i + 3);
      int s4 = __shfl(me.x, i + 4), s5 = __shfl(me.x, i + 5);
      int s6 = __shfl(me.x, i + 6), s7 = __shfl(me.x, i + 7);
      float c0 = __int_as_float(__shfl(me.y, i));
      float c1 = __int_as_float(__shfl(me.y, i + 1));
      float c2 = __int_as_float(__shfl(me.y, i + 2));
      float c3 = __int_as_float(__shfl(me.y, i + 3));
      float c4 = __int_as_float(__shfl(me.y, i + 4));
      float c5 = __int_as_float(__shfl(me.y, i + 5));
      float c6 = __int_as_float(__shfl(me.y, i + 6));
      float c7 = __int_as_float(__shfl(me.y, i + 7));
      uint2 v0 = *((const uint2*)(h + (size_t)s0 * 256) + lane);
      uint2 v1 = *((const uint2*)(h + (size_t)s1 * 256) + lane);
      uint2 v2 = *((const uint2*)(h + (size_t)s2 * 256) + lane);
      uint2 v3 = *((const uint2*)(h + (size_t)s3 * 256) + lane);
      uint2 v4 = *((const uint2*)(h + (size_t)s4 * 256) + lane);
      uint2 v5 = *((const uint2*)(h + (size_t)s5 * 256) + lane);
      uint2 v6 = *((const uint2*)(h + (size_t)s6 * 256) + lane);
      uint2 v7 = *((const uint2*)(h + (size_t)s7 * 256) + lane);
      acc256(v0, c0, sc, sh, ax0, ay0, az0, aw0);
      acc256(v1, c1, sc, sh, ax1, ay1, az1, aw1);
      acc256(v2, c2, sc, sh, ax2, ay2, az2, aw2);
      acc256(v3, c3, sc, sh, ax3, ay3, az3, aw3);
      acc256(v4, c4, sc, sh, ax0, ay0, az0, aw0);
      acc256(v5, c5, sc, sh, ax1, ay1, az1, aw1);
      acc256(v6, c6, sc, sh, ax2, ay2, az2, aw2);
      acc256(v7, c7, sc, sh, ax3, ay3, az3, aw3);
    }
    for (; i + 4 <= k; i += 4) {
      int s0 = __shfl(me.x, i),     s1 = __shfl(me.x, i + 1);
      int s2 = __shfl(me.x, i + 2), s3 = __shfl(me.x, i + 3);
      float c0 = __int_as_float(__shfl(me.y, i));
      float c1 = __int_as_float(__shfl(me.y, i + 1));
      float c2 = __int_as_float(__shfl(me.y, i + 2));
      float c3 = __int_as_float(__shfl(me.y, i + 3));
      uint2 v0 = *((const uint2*)(h + (size_t)s0 * 256) + lane);
      uint2 v1 = *((const uint2*)(h + (size_t)s1 * 256) + lane);
      uint2 v2 = *((const uint2*)(h + (size_t)s2 * 256) + lane);
      uint2 v3 = *((const uint2*)(h + (size_t)s3 * 256) + lane);
      acc256(v0, c0, sc, sh, ax0, ay0, az0, aw0);
      acc256(v1, c1, sc, sh, ax1, ay1, az1, aw1);
      acc256(v2, c2, sc, sh, ax2, ay2, az2, aw2);
      acc256(v3, c3, sc, sh, ax3, ay3, az3, aw3);
    }
    for (; i < k; ++i) {
      int s = __shfl(me.x, i);
      float co = __int_as_float(__shfl(me.y, i));
      uint2 v = *((const uint2*)(h + (size_t)s * 256) + lane);
      acc256(v, co, sc, sh, ax0, ay0, az0, aw0);
    }
  }
  float ax = (ax0 + ax1) + (ax2 + ax3), ay = (ay0 + ay1) + (ay2 + ay3);
  float az = (az0 + az1) + (az2 + az3), aw = (aw0 + aw1) + (aw2 + aw3);
  unsigned int lo = (unsigned int)f2bf(ax) | ((unsigned int)f2bf(ay) << 16);
  unsigned int hi = (unsigned int)f2bf(az) | ((unsigned int)f2bf(aw) << 16);
  *((uint2*)(out + (size_t)n * 256) + lane) = make_uint2(lo, hi);
}

__device__ __forceinline__ void acc128(unsigned int v, float co, float& ax, float& ay) {
  ax += co * bf2f((unsigned short)(v & 0xffff));
  ay += co * bf2f((unsigned short)(v >> 16));
}

__global__ __launch_bounds__(256) void agg128_bf(const unsigned short* __restrict__ h,
                                                 const int* __restrict__ offs,
                                                 const int2* __restrict__ csr,
                                                 const float* __restrict__ dinv,
                                                 unsigned short* __restrict__ out, int N) {
  int n = (blockIdx.x * 256 + threadIdx.x) >> 6;
  int lane = threadIdx.x & 63;
  if (n >= N) return;
  float di = dinv[n];
  float self = di * di;
  float ax0 = 0.f, ay0 = 0.f, ax1 = 0.f, ay1 = 0.f;
  float ax2 = 0.f, ay2 = 0.f, ax3 = 0.f, ay3 = 0.f;
  {
    unsigned int v = *((const unsigned int*)(h + (size_t)n * 128) + lane);
    acc128(v, self, ax0, ay0);
  }
  int e0 = offs[n], e1 = offs[n + 1];
  for (int eb = e0; eb < e1; eb += 64) {
    int k = min(64, e1 - eb);
    int2 me = make_int2(0, 0);
    if (lane < k) me = csr[eb + lane];
    int i = 0;
    for (; i + 8 <= k; i += 8) {
      int s0 = __shfl(me.x, i),     s1 = __shfl(me.x, i + 1);
      int s2 = __shfl(me.x, i + 2), s3 = __shfl(me.x, i + 3);
      int s4 = __shfl(me.x, i + 4), s5 = __shfl(me.x, i + 5);
      int s6 = __shfl(me.x, i + 6), s7 = __shfl(me.x, i + 7);
      float c0 = __int_as_float(__shfl(me.y, i));
      float c1 = __int_as_float(__shfl(me.y, i + 1));
      float c2 = __int_as_float(__shfl(me.y, i + 2));
      float c3 = __int_as_float(__shfl(me.y, i + 3));
      float c4 = __int_as_float(__shfl(me.y, i + 4));
      float c5 = __int_as_float(__shfl(me.y, i + 5));
      float c6 = __int_as_float(__shfl(me.y, i + 6));
      float c7 = __int_as_float(__shfl(me.y, i + 7));
      unsigned int v0 = *((const unsigned int*)(h + (size_t)s0 * 128) + lane);
      unsigned int v1 = *((const unsigned int*)(h + (size_t)s1 * 128) + lane);
      unsigned int v2 = *((const unsigned int*)(h + (size_t)s2 * 128) + lane);
      unsigned int v3 = *((const unsigned int*)(h + (size_t)s3 * 128) + lane);
      unsigned int v4 = *((const unsigned int*)(h + (size_t)s4 * 128) + lane);
      unsigned int v5 = *((const unsigned int*)(h + (size_t)s5 * 128) + lane);
      unsigned int v6 = *((const unsigned int*)(h + (size_t)s6 * 128) + lane);
      unsigned int v7 = *((const unsigned int*)(h + (size_t)s7 * 128) + lane);
      acc128(v0, c0, ax0, ay0); acc128(v1, c1, ax1, ay1);
      acc128(v2, c2, ax2, ay2); acc128(v3, c3, ax3, ay3);
      acc128(v4, c4, ax0, ay0); acc128(v5, c5, ax1, ay1);
      acc128(v6, c6, ax2, ay2); acc128(v7, c7, ax3, ay3);
    }
    for (; i + 4 <= k; i += 4) {
      int s0 = __shfl(me.x, i),     s1 = __shfl(me.x, i + 1);
      int s2 = __shfl(me.x, i + 2), s3 = __shfl(me.x, i + 3);
      float c0 = __int_as_float(__shfl(me.y, i));
      float c1 = __int_as_float(__shfl(me.y, i + 1));
      float c2 = __int_as_float(__shfl(me.y, i + 2));
      float c3 = __int_as_float(__shfl(me.y, i + 3));
      unsigned int v0 = *((const unsigned int*)(h + (size_t)s0 * 128) + lane);
      unsigned int v1 = *((const unsigned int*)(h + (size_t)s1 * 128) + lane);
      unsigned int v2 = *((const unsigned int*)(h + (size_t)s2 * 128) + lane);
      unsigned int v3 = *((const unsigned int*)(h + (size_t)s3 * 128) + lane);
      acc128(v0, c0, ax0, ay0); acc128(v1, c1, ax1, ay1);
      acc128(v2, c2, ax2, ay2); acc128(v3, c3, ax3, ay3);
    }
    for (; i < k; ++i) {
      int s = __shfl(me.x, i);
      float co = __int_as_float(__shfl(me.y, i));
      unsigned int v = *((const unsigned int*)(h + (size_t)s * 128) + lane);
      acc128(v, co, ax0, ay0);
    }
  }
  float ax = (ax0 + ax1) + (ax2 + ax3), ay = (ay0 + ay1) + (ay2 + ay3);
  *((unsigned int*)(out + (size_t)n * 128) + lane) =
      (unsigned int)f2bf(ax) | ((unsigned int)f2bf(ay) << 16);
}

// ---------------- barrier-free register GEMM + fused BN stats ----------------
// C[Mpad,256] = A[Mpad,K] @ W[K,256] with Wt=[256][K] bf16 (L2-resident, <=128KB).
// 512 threads = 8 waves; wave w owns rows [bid*128 + w*16, +16) x all 256 cols.
// acc[16] f32x4; A-frag + 16 B-frags loaded per K-step straight from global;
// no LDS staging, no K-loop barriers. LDS only for the stats block-reduce.

__global__ __launch_bounds__(512, 2) void gemm_bf(const unsigned short* __restrict__ A,
                                                  const unsigned short* __restrict__ Wt,
                                                  unsigned short* __restrict__ C,
                                                  int K,
                                                  float* __restrict__ sums,
                                                  float* __restrict__ sumsq) {
  __shared__ float red_s[8][256];
  __shared__ float red_q[8][256];
  int t = threadIdx.x;
  int w = t >> 6, lane = t & 63;
  int l16 = lane & 15, lhi = lane >> 4;
  int row16 = blockIdx.x * 128 + w * 16;   // wave's row base
  f32x4 acc[16] = {};
  const unsigned short* Arow = A + (size_t)(row16 + l16) * K + lhi * 8;
  for (int kk = 0; kk < K; kk += 32) {
    bf16x8 a = *(const bf16x8*)(Arow + kk);
#pragma unroll
    for (int j = 0; j < 16; ++j) {
      bf16x8 b = *(const bf16x8*)(Wt + (size_t)(j * 16 + l16) * K + kk + lhi * 8);
      acc[j] = __builtin_amdgcn_mfma_f32_16x16x32_bf16(a, b, acc[j], 0, 0, 0);
    }
  }
  // C write: row = row16 + lhi*4 + rr, col = j*16 + l16
#pragma unroll
  for (int rr = 0; rr < 4; ++rr) {
    size_t o = (size_t)(row16 + lhi * 4 + rr) * 256 + l16;
#pragma unroll
    for (int j = 0; j < 16; ++j) C[o + j * 16] = f2bf(acc[j][rr]);
  }
  // per-wave column stats -> LDS -> block reduce -> atomics (512/block)
#pragma unroll
  for (int j = 0; j < 16; ++j) {
    float s = 0.f, s2 = 0.f;
#pragma unroll
    for (int rr = 0; rr < 4; ++rr) { float v = acc[j][rr]; s += v; s2 += v * v; }
    s  += __shfl_xor(s, 16);  s  += __shfl_xor(s, 32);
    s2 += __shfl_xor(s2, 16); s2 += __shfl_xor(s2, 32);
    if (lhi == 0) { red_s[w][j * 16 + l16] = s; red_q[w][j * 16 + l16] = s2; }
  }
  __syncthreads();
  if (t < 256) {
    float s = 0.f;
#pragma unroll
    for (int ww = 0; ww < 8; ++ww) s += red_s[ww][t];
    atomicAdd(&sums[t], s);
  } else {
    int c = t - 256;
    float s2 = 0.f;
#pragma unroll
    for (int ww = 0; ww < 8; ++ww) s2 += red_q[ww][c];
    atomicAdd(&sumsq[c], s2);
  }
}

// ---------------- pool (BN2+ReLU fused, in-block finalize) + classifier ----------------

__global__ __launch_bounds__(256) void pool_final(const unsigned short* __restrict__ h,
                                                  const unsigned int* __restrict__ gstart,
                                                  const float* __restrict__ sums,
                                                  const float* __restrict__ sumsq,
                                                  const float* __restrict__ gamma,
                                                  const float* __restrict__ beta,
                                                  float invN,
                                                  const float* __restrict__ Wl,
                                                  const float* __restrict__ bl,
                                                  float* __restrict__ out, int NC) {
  __shared__ float s_sc[256], s_sh[256];
  __shared__ float4 part[4][64];
  __shared__ float p[256];
  int t = threadIdx.x, w = t >> 6, lane = t & 63;
  {
    float mean = sums[t] * invN;
    float var = sumsq[t] * invN - mean * mean;
    float scv = gamma[t] * rsqrtf(var + BN_EPS);
    s_sc[t] = scv;
    s_sh[t] = beta[t] - mean * scv;
  }
  __syncthreads();
  float4 sc = *(const float4*)&s_sc[lane * 4];
  float4 sh = *(const float4*)&s_sh[lane * 4];
  int g = blockIdx.x;
  int gs = (int)gstart[g], ge = (int)gstart[g + 1];
  float ax = 0.f, ay = 0.f, az = 0.f, aw = 0.f;
  for (int r = gs + w; r < ge; r += 4) {
    uint2 v = *((const uint2*)(h + (size_t)r * 256) + lane);
    ax += fmaxf(bf2f((unsigned short)(v.x & 0xffff)) * sc.x + sh.x, 0.f);
    ay += fmaxf(bf2f((unsigned short)(v.x >> 16)) * sc.y + sh.y, 0.f);
    az += fmaxf(bf2f((unsigned short)(v.y & 0xffff)) * sc.z + sh.z, 0.f);
    aw += fmaxf(bf2f((unsigned short)(v.y >> 16)) * sc.w + sh.w, 0.f);
  }
  part[w][lane] = make_float4(ax, ay, az, aw);
  __syncthreads();
  if (t < 64) {
    float inv = 1.0f / fmaxf((float)(ge - gs), 1.0f);
    float4 s0 = part[0][t], s1 = part[1][t], s2 = part[2][t], s3 = part[3][t];
    float4 r;
    r.x = (s0.x + s1.x + s2.x + s3.x) * inv;
    r.y = (s0.y + s1.y + s2.y + s3.y) * inv;
    r.z = (s0.z + s1.z + s2.z + s3.z) * inv;
    r.w = (s0.w + s1.w + s2.w + s3.w) * inv;
    *(float4*)&p[t * 4] = r;
  }
  __syncthreads();
  if (t < NC) {
    float s = bl[t];
    for (int k = 0; k < 256; ++k) s += p[k] * Wl[k * NC + t];
    out[g * NC + t] = s;
  }
}

// ---------------- launcher ----------------

extern "C" void kernel_launch(void* const* d_in, const int* in_sizes, int n_in,
                              void* d_out, int out_size, void* d_ws, size_t ws_size,
                              hipStream_t stream) {
  const float* x      = (const float*)d_in[0];
  const int*   ei     = (const int*)d_in[1];
  const int*   batch  = (const int*)d_in[2];
  const float* W0     = (const float*)d_in[3];
  const float* gamma0 = (const float*)d_in[5];
  const float* beta0  = (const float*)d_in[6];
  const float* W1     = (const float*)d_in[7];
  const float* gamma1 = (const float*)d_in[9];
  const float* beta1  = (const float*)d_in[10];
  const float* W2     = (const float*)d_in[11];
  const float* gamma2 = (const float*)d_in[13];
  const float* beta2  = (const float*)d_in[14];
  const float* Wl     = (const float*)d_in[15];
  const float* bl     = (const float*)d_in[16];
  float* out = (float*)d_out;

  int N = in_sizes[0] / 128;  // 50000
  int E = in_sizes[1] / 2;    // 800000
  int G = 128;
  int NC = 40;
  int Mpad = ((N + 127) / 128) * 128;  // 50048
  float invN = 1.0f / (float)N;
  const int* src = ei;
  const int* dst = ei + E;

  char* p = (char*)d_ws;
  auto alloc = [&](size_t bytes) -> void* {
    void* r = (void*)p;
    p += (bytes + 255) & ~(size_t)255;
    return r;
  };
  unsigned short* xb  = (unsigned short*)alloc((size_t)N * 128 * 2);
  unsigned short* hA  = (unsigned short*)alloc((size_t)Mpad * 256 * 2);
  unsigned short* hB  = (unsigned short*)alloc((size_t)Mpad * 256 * 2);
  unsigned short* Wt0 = (unsigned short*)alloc((size_t)256 * 128 * 2);
  unsigned short* Wt1 = (unsigned short*)alloc((size_t)256 * 256 * 2);
  unsigned short* Wt2 = (unsigned short*)alloc((size_t)256 * 256 * 2);
  int2*  csr      = (int2*) alloc((size_t)E * 8);
  int*   cc       = (int*)  alloc((size_t)(2 * N + 6 * 256) * 4);
  int*   counts   = cc;
  int*   cursor   = cc + N;
  float* stats    = (float*)(cc + 2 * N);
  float* sums0 = stats + 0 * 256, *sumsq0 = stats + 1 * 256;
  float* sums1 = stats + 2 * 256, *sumsq1 = stats + 3 * 256;
  float* sums2 = stats + 4 * 256, *sumsq2 = stats + 5 * 256;
  int*   offs     = (int*)  alloc((size_t)(N + 1) * 4);
  float* dinv     = (float*)alloc((size_t)N * 4);
  int*   blkSum   = (int*)  alloc(64 * 4);
  int*   blkOff   = (int*)  alloc(64 * 4);
  unsigned int* gstart = (unsigned int*)alloc((size_t)(G + 1) * 4);

  // ---- init ----
  hipMemsetAsync(cc, 0, (size_t)(2 * N + 6 * 256) * 4, stream);
  hipMemsetAsync(gstart, 0xFF, (size_t)(G + 1) * 4, stream);

  // ---- graph structure ----
  count_boundary<<<(E + 255) / 256, 256, 0, stream>>>(dst, E, counts, batch, N, gstart);
  int nb = (N + 1023) / 1024;
  scan1<<<nb, 256, 0, stream>>>(counts, N, offs, blkSum, dinv);
  scan2_fix<<<1, 64, 0, stream>>>(blkSum, nb, blkOff, offs, N, gstart, G);
  scan3<<<nb, 1024, 0, stream>>>(offs, N, blkOff);

  // ---- fill CSR + conversions + pad zeroing ----
  {
    int nx4 = N * 32;
    int npad128_8 = (Mpad - N) * 128 / 8;
    int npad256_8 = (Mpad - N) * 256 / 8;
    long long total = (long long)E + nx4 + 128 * 256 + 256 * 256 + 256 * 256
                    + npad128_8 + npad256_8;
    int blocks = (int)((total + 255) / 256);
    fill_cvt<<<blocks, 256, 0, stream>>>(src, dst, E, offs, cursor, dinv, csr,
                                         x, xb, nx4, W0, Wt0, W1, Wt1, W2, Wt2,
                                         hA + (size_t)N * 128, npad128_8,
                                         hA + (size_t)N * 256, npad256_8);
  }

  int aggBlocks = (N + 3) / 4;
  int gemmBlocks = Mpad / 128;  // 391

  // ---- layer 0 ----
  agg128_bf<<<aggBlocks, 256, 0, stream>>>(xb, offs, csr, dinv, hA, N);
  gemm_bf<<<gemmBlocks, 512, 0, stream>>>(hA, Wt0, hB, 128, sums0, sumsq0);

  // ---- layer 1 (BN0 finalize + ReLU fused into gather prologue) ----
  agg256_bf<<<aggBlocks, 256, 0, stream>>>(hB, offs, csr, dinv, sums0, sumsq0,
                                           gamma0, beta0, invN, hA, N);
  gemm_bf<<<gemmBlocks, 512, 0, stream>>>(hA, Wt1, hB, 256, sums1, sumsq1);

  // ---- layer 2 ----
  agg256_bf<<<aggBlocks, 256, 0, stream>>>(hB, offs, csr, dinv, sums1, sumsq1,
                                           gamma1, beta1, invN, hA, N);
  gemm_bf<<<gemmBlocks, 512, 0, stream>>>(hA, Wt2, hB, 256, sums2, sumsq2);

  // ---- pool (BN2 finalize in-block) + classifier ----
  pool_final<<<G, 256, 0, stream>>>(hB, gstart, sums2, sumsq2, gamma2, beta2, invN,
                                    Wl, bl, out, NC);
}

// Round 9
// 524.143 us; speedup vs baseline: 1.1006x; 1.1006x over previous
//
#include <hip/hip_runtime.h>

#define BN_EPS 1e-5f

typedef __attribute__((ext_vector_type(8))) short bf16x8;
typedef __attribute__((ext_vector_type(4))) float f32x4;

__device__ __forceinline__ float bf2f(unsigned short u) {
  return __uint_as_float(((unsigned int)u) << 16);
}
__device__ __forceinline__ unsigned short f2bf(float f) {
  unsigned int u = __float_as_uint(f);
  u = u + 0x7FFFu + ((u >> 16) & 1u);   // round-to-nearest-even
  return (unsigned short)(u >> 16);
}

// async global->LDS, 16B per lane; LDS dest = (wave-uniform base) + lane*16
__device__ __forceinline__ void gload16(const unsigned short* g, unsigned short* l) {
  __builtin_amdgcn_global_load_lds(
      (const __attribute__((address_space(1))) unsigned int*)g,
      (__attribute__((address_space(3))) unsigned int*)l, 16, 0, 0);
}

// ---------------- graph structure ----------------

__global__ __launch_bounds__(256) void count_boundary(const int* __restrict__ dst, int E,
                                                      int* __restrict__ counts,
                                                      const int* __restrict__ batch, int N,
                                                      unsigned int* __restrict__ gstart) {
  int e = blockIdx.x * 256 + threadIdx.x;
  if (e < E) atomicAdd(&counts[dst[e]], 1);
  if (e < N) {
    if (e == 0 || batch[e] != batch[e - 1]) atomicMin(&gstart[batch[e]], (unsigned int)e);
  }
}

__global__ __launch_bounds__(256) void scan1(const int* __restrict__ counts, int N,
                                             int* __restrict__ offs, int* __restrict__ blkSum,
                                             float* __restrict__ dinv) {
  __shared__ int sd[256];
  int t = threadIdx.x;
  int i0 = blockIdx.x * 1024 + t * 4;
  int v0 = (i0 + 0 < N) ? counts[i0 + 0] : 0;
  int v1 = (i0 + 1 < N) ? counts[i0 + 1] : 0;
  int v2 = (i0 + 2 < N) ? counts[i0 + 2] : 0;
  int v3 = (i0 + 3 < N) ? counts[i0 + 3] : 0;
  if (i0 + 0 < N) dinv[i0 + 0] = rsqrtf((float)(v0 + 1));
  if (i0 + 1 < N) dinv[i0 + 1] = rsqrtf((float)(v1 + 1));
  if (i0 + 2 < N) dinv[i0 + 2] = rsqrtf((float)(v2 + 1));
  if (i0 + 3 < N) dinv[i0 + 3] = rsqrtf((float)(v3 + 1));
  int tot = v0 + v1 + v2 + v3;
  sd[t] = tot;
  __syncthreads();
  for (int off = 1; off < 256; off <<= 1) {
    int x = (t >= off) ? sd[t - off] : 0;
    __syncthreads();
    sd[t] += x;
    __syncthreads();
  }
  int excl = sd[t] - tot;
  if (i0 + 0 < N) offs[i0 + 0] = excl;
  if (i0 + 1 < N) offs[i0 + 1] = excl + v0;
  if (i0 + 2 < N) offs[i0 + 2] = excl + v0 + v1;
  if (i0 + 3 < N) offs[i0 + 3] = excl + v0 + v1 + v2;
  if (t == 255) blkSum[blockIdx.x] = sd[255];
}

__global__ void scan2_fix(const int* __restrict__ blkSum, int nb, int* __restrict__ blkOff,
                          int* __restrict__ offs, int N,
                          unsigned int* __restrict__ gstart, int G) {
  if (blockIdx.x != 0) return;
  if (threadIdx.x == 0) {
    int run = 0;
    for (int b = 0; b < nb; ++b) { blkOff[b] = run; run += blkSum[b]; }
    offs[N] = run;
  } else if (threadIdx.x == 1) {
    gstart[G] = (unsigned int)N;
    for (int g = G - 1; g >= 0; --g)
      if (gstart[g] == 0xFFFFFFFFu) gstart[g] = gstart[g + 1];
  }
}

__global__ __launch_bounds__(1024) void scan3(int* __restrict__ offs, int N,
                                              const int* __restrict__ blkOff) {
  int i = blockIdx.x * 1024 + threadIdx.x;
  if (i < N) offs[i] += blkOff[blockIdx.x];
}

// ---------------- fill CSR + dtype conversions + pad zeroing (one dispatch) ----------------

__global__ __launch_bounds__(256) void fill_cvt(const int* __restrict__ src,
                                                const int* __restrict__ dst, int E,
                                                const int* __restrict__ offs,
                                                int* __restrict__ cursor,
                                                const float* __restrict__ dinv,
                                                int2* __restrict__ csr,
                                                const float* __restrict__ x,
                                                unsigned short* __restrict__ xb, int nx4,
                                                const float* __restrict__ W0,
                                                unsigned short* __restrict__ Wt0,
                                                const float* __restrict__ W1,
                                                unsigned short* __restrict__ Wt1,
                                                const float* __restrict__ W2,
                                                unsigned short* __restrict__ Wt2,
                                                unsigned short* __restrict__ pad128, int npad128_8,
                                                unsigned short* __restrict__ pad256, int npad256_8) {
  long long idx = (long long)blockIdx.x * 256 + threadIdx.x;
  if (idx < E) {
    int e = (int)idx;
    int s = src[e], d = dst[e];
    int pos = offs[d] + atomicAdd(&cursor[d], 1);
    csr[pos] = make_int2(s, __float_as_int(dinv[s] * dinv[d]));
    return;
  }
  idx -= E;
  if (idx < nx4) {
    float4 v = ((const float4*)x)[idx];
    unsigned int lo = (unsigned int)f2bf(v.x) | ((unsigned int)f2bf(v.y) << 16);
    unsigned int hi = (unsigned int)f2bf(v.z) | ((unsigned int)f2bf(v.w) << 16);
    ((uint2*)xb)[idx] = make_uint2(lo, hi);
    return;
  }
  idx -= nx4;
  if (idx < 128 * 256) {
    int k = (int)(idx >> 8), n = (int)(idx & 255);
    Wt0[n * 128 + k] = f2bf(W0[k * 256 + n]);
    return;
  }
  idx -= 128 * 256;
  if (idx < 256 * 256) {
    int k = (int)(idx >> 8), n = (int)(idx & 255);
    Wt1[n * 256 + k] = f2bf(W1[k * 256 + n]);
    return;
  }
  idx -= 256 * 256;
  if (idx < 256 * 256) {
    int k = (int)(idx >> 8), n = (int)(idx & 255);
    Wt2[n * 256 + k] = f2bf(W2[k * 256 + n]);
    return;
  }
  idx -= 256 * 256;
  if (idx < npad128_8) { ((uint4*)pad128)[idx] = make_uint4(0, 0, 0, 0); return; }
  idx -= npad128_8;
  if (idx < npad256_8) { ((uint4*)pad256)[idx] = make_uint4(0, 0, 0, 0); return; }
}

// ---------------- BN finalize + ReLU, materialized in place (rows < N only) ----------------
// Pad rows must remain exactly zero (they feed the next GEMM's fused stats),
// so this only touches the first N*32 uint4's.

__global__ __launch_bounds__(256) void bn_relu(unsigned short* __restrict__ h,
                                               const float* __restrict__ sums,
                                               const float* __restrict__ sumsq,
                                               const float* __restrict__ gamma,
                                               const float* __restrict__ beta,
                                               float invN, int total4) {
  __shared__ float s_sc[256], s_sh[256];
  int t = threadIdx.x;
  {
    float mean = sums[t] * invN;
    float var = sumsq[t] * invN - mean * mean;
    float scv = gamma[t] * rsqrtf(var + BN_EPS);
    s_sc[t] = scv;
    s_sh[t] = beta[t] - mean * scv;
  }
  __syncthreads();
  int idx = blockIdx.x * 256 + t;
  if (idx >= total4) return;
  int c0 = (idx & 31) * 8;
  uint4 v = ((const uint4*)h)[idx];
  unsigned int r[4];
  unsigned int in[4] = {v.x, v.y, v.z, v.w};
#pragma unroll
  for (int q = 0; q < 4; ++q) {
    float f0 = fmaxf(bf2f((unsigned short)(in[q] & 0xffff)) * s_sc[c0 + 2 * q] + s_sh[c0 + 2 * q], 0.f);
    float f1 = fmaxf(bf2f((unsigned short)(in[q] >> 16)) * s_sc[c0 + 2 * q + 1] + s_sh[c0 + 2 * q + 1], 0.f);
    r[q] = (unsigned int)f2bf(f0) | ((unsigned int)f2bf(f1) << 16);
  }
  ((uint4*)h)[idx] = make_uint4(r[0], r[1], r[2], r[3]);
}

// ---------------- aggregation (pure gather, CSR by dst), one wave per node ----------------
// 8-edge unroll, 4 accumulator chains, 8 gathers in flight.

__device__ __forceinline__ void acc256(uint2 v, float co,
                                       float& ax, float& ay, float& az, float& aw) {
  ax += co * bf2f((unsigned short)(v.x & 0xffff));
  ay += co * bf2f((unsigned short)(v.x >> 16));
  az += co * bf2f((unsigned short)(v.y & 0xffff));
  aw += co * bf2f((unsigned short)(v.y >> 16));
}

__global__ __launch_bounds__(256) void agg256_bf(const unsigned short* __restrict__ h,
                                                 const int* __restrict__ offs,
                                                 const int2* __restrict__ csr,
                                                 const float* __restrict__ dinv,
                                                 unsigned short* __restrict__ out, int N) {
  int n = (blockIdx.x * 256 + threadIdx.x) >> 6;
  int lane = threadIdx.x & 63;
  if (n >= N) return;
  float di = dinv[n];
  float self = di * di;
  float ax0 = 0.f, ay0 = 0.f, az0 = 0.f, aw0 = 0.f;
  float ax1 = 0.f, ay1 = 0.f, az1 = 0.f, aw1 = 0.f;
  float ax2 = 0.f, ay2 = 0.f, az2 = 0.f, aw2 = 0.f;
  float ax3 = 0.f, ay3 = 0.f, az3 = 0.f, aw3 = 0.f;
  {
    uint2 v = *((const uint2*)(h + (size_t)n * 256) + lane);
    acc256(v, self, ax0, ay0, az0, aw0);
  }
  int e0 = offs[n], e1 = offs[n + 1];
  for (int eb = e0; eb < e1; eb += 64) {
    int k = min(64, e1 - eb);
    int2 me = make_int2(0, 0);
    if (lane < k) me = csr[eb + lane];
    int i = 0;
    for (; i + 8 <= k; i += 8) {
      int s0 = __shfl(me.x, i),     s1 = __shfl(me.x, i + 1);
      int s2 = __shfl(me.x, i + 2), s3 = __shfl(me.x, i + 3);
      int s4 = __shfl(me.x, i + 4), s5 = __shfl(me.x, i + 5);
      int s6 = __shfl(me.x, i + 6), s7 = __shfl(me.x, i + 7);
      float c0 = __int_as_float(__shfl(me.y, i));
      float c1 = __int_as_float(__shfl(me.y, i + 1));
      float c2 = __int_as_float(__shfl(me.y, i + 2));
      float c3 = __int_as_float(__shfl(me.y, i + 3));
      float c4 = __int_as_float(__shfl(me.y, i + 4));
      float c5 = __int_as_float(__shfl(me.y, i + 5));
      float c6 = __int_as_float(__shfl(me.y, i + 6));
      float c7 = __int_as_float(__shfl(me.y, i + 7));
      uint2 v0 = *((const uint2*)(h + (size_t)s0 * 256) + lane);
      uint2 v1 = *((const uint2*)(h + (size_t)s1 * 256) + lane);
      uint2 v2 = *((const uint2*)(h + (size_t)s2 * 256) + lane);
      uint2 v3 = *((const uint2*)(h + (size_t)s3 * 256) + lane);
      uint2 v4 = *((const uint2*)(h + (size_t)s4 * 256) + lane);
      uint2 v5 = *((const uint2*)(h + (size_t)s5 * 256) + lane);
      uint2 v6 = *((const uint2*)(h + (size_t)s6 * 256) + lane);
      uint2 v7 = *((const uint2*)(h + (size_t)s7 * 256) + lane);
      acc256(v0, c0, ax0, ay0, az0, aw0);
      acc256(v1, c1, ax1, ay1, az1, aw1);
      acc256(v2, c2, ax2, ay2, az2, aw2);
      acc256(v3, c3, ax3, ay3, az3, aw3);
      acc256(v4, c4, ax0, ay0, az0, aw0);
      acc256(v5, c5, ax1, ay1, az1, aw1);
      acc256(v6, c6, ax2, ay2, az2, aw2);
      acc256(v7, c7, ax3, ay3, az3, aw3);
    }
    for (; i + 4 <= k; i += 4) {
      int s0 = __shfl(me.x, i),     s1 = __shfl(me.x, i + 1);
      int s2 = __shfl(me.x, i + 2), s3 = __shfl(me.x, i + 3);
      float c0 = __int_as_float(__shfl(me.y, i));
      float c1 = __int_as_float(__shfl(me.y, i + 1));
      float c2 = __int_as_float(__shfl(me.y, i + 2));
      float c3 = __int_as_float(__shfl(me.y, i + 3));
      uint2 v0 = *((const uint2*)(h + (size_t)s0 * 256) + lane);
      uint2 v1 = *((const uint2*)(h + (size_t)s1 * 256) + lane);
      uint2 v2 = *((const uint2*)(h + (size_t)s2 * 256) + lane);
      uint2 v3 = *((const uint2*)(h + (size_t)s3 * 256) + lane);
      acc256(v0, c0, ax0, ay0, az0, aw0);
      acc256(v1, c1, ax1, ay1, az1, aw1);
      acc256(v2, c2, ax2, ay2, az2, aw2);
      acc256(v3, c3, ax3, ay3, az3, aw3);
    }
    for (; i < k; ++i) {
      int s = __shfl(me.x, i);
      float co = __int_as_float(__shfl(me.y, i));
      uint2 v = *((const uint2*)(h + (size_t)s * 256) + lane);
      acc256(v, co, ax0, ay0, az0, aw0);
    }
  }
  float ax = (ax0 + ax1) + (ax2 + ax3), ay = (ay0 + ay1) + (ay2 + ay3);
  float az = (az0 + az1) + (az2 + az3), aw = (aw0 + aw1) + (aw2 + aw3);
  unsigned int lo = (unsigned int)f2bf(ax) | ((unsigned int)f2bf(ay) << 16);
  unsigned int hi = (unsigned int)f2bf(az) | ((unsigned int)f2bf(aw) << 16);
  *((uint2*)(out + (size_t)n * 256) + lane) = make_uint2(lo, hi);
}

__device__ __forceinline__ void acc128(unsigned int v, float co, float& ax, float& ay) {
  ax += co * bf2f((unsigned short)(v & 0xffff));
  ay += co * bf2f((unsigned short)(v >> 16));
}

__global__ __launch_bounds__(256) void agg128_bf(const unsigned short* __restrict__ h,
                                                 const int* __restrict__ offs,
                                                 const int2* __restrict__ csr,
                                                 const float* __restrict__ dinv,
                                                 unsigned short* __restrict__ out, int N) {
  int n = (blockIdx.x * 256 + threadIdx.x) >> 6;
  int lane = threadIdx.x & 63;
  if (n >= N) return;
  float di = dinv[n];
  float self = di * di;
  float ax0 = 0.f, ay0 = 0.f, ax1 = 0.f, ay1 = 0.f;
  float ax2 = 0.f, ay2 = 0.f, ax3 = 0.f, ay3 = 0.f;
  {
    unsigned int v = *((const unsigned int*)(h + (size_t)n * 128) + lane);
    acc128(v, self, ax0, ay0);
  }
  int e0 = offs[n], e1 = offs[n + 1];
  for (int eb = e0; eb < e1; eb += 64) {
    int k = min(64, e1 - eb);
    int2 me = make_int2(0, 0);
    if (lane < k) me = csr[eb + lane];
    int i = 0;
    for (; i + 8 <= k; i += 8) {
      int s0 = __shfl(me.x, i),     s1 = __shfl(me.x, i + 1);
      int s2 = __shfl(me.x, i + 2), s3 = __shfl(me.x, i + 3);
      int s4 = __shfl(me.x, i + 4), s5 = __shfl(me.x, i + 5);
      int s6 = __shfl(me.x, i + 6), s7 = __shfl(me.x, i + 7);
      float c0 = __int_as_float(__shfl(me.y, i));
      float c1 = __int_as_float(__shfl(me.y, i + 1));
      float c2 = __int_as_float(__shfl(me.y, i + 2));
      float c3 = __int_as_float(__shfl(me.y, i + 3));
      float c4 = __int_as_float(__shfl(me.y, i + 4));
      float c5 = __int_as_float(__shfl(me.y, i + 5));
      float c6 = __int_as_float(__shfl(me.y, i + 6));
      float c7 = __int_as_float(__shfl(me.y, i + 7));
      unsigned int v0 = *((const unsigned int*)(h + (size_t)s0 * 128) + lane);
      unsigned int v1 = *((const unsigned int*)(h + (size_t)s1 * 128) + lane);
      unsigned int v2 = *((const unsigned int*)(h + (size_t)s2 * 128) + lane);
      unsigned int v3 = *((const unsigned int*)(h + (size_t)s3 * 128) + lane);
      unsigned int v4 = *((const unsigned int*)(h + (size_t)s4 * 128) + lane);
      unsigned int v5 = *((const unsigned int*)(h + (size_t)s5 * 128) + lane);
      unsigned int v6 = *((const unsigned int*)(h + (size_t)s6 * 128) + lane);
      unsigned int v7 = *((const unsigned int*)(h + (size_t)s7 * 128) + lane);
      acc128(v0, c0, ax0, ay0); acc128(v1, c1, ax1, ay1);
      acc128(v2, c2, ax2, ay2); acc128(v3, c3, ax3, ay3);
      acc128(v4, c4, ax0, ay0); acc128(v5, c5, ax1, ay1);
      acc128(v6, c6, ax2, ay2); acc128(v7, c7, ax3, ay3);
    }
    for (; i + 4 <= k; i += 4) {
      int s0 = __shfl(me.x, i),     s1 = __shfl(me.x, i + 1);
      int s2 = __shfl(me.x, i + 2), s3 = __shfl(me.x, i + 3);
      float c0 = __int_as_float(__shfl(me.y, i));
      float c1 = __int_as_float(__shfl(me.y, i + 1));
      float c2 = __int_as_float(__shfl(me.y, i + 2));
      float c3 = __int_as_float(__shfl(me.y, i + 3));
      unsigned int v0 = *((const unsigned int*)(h + (size_t)s0 * 128) + lane);
      unsigned int v1 = *((const unsigned int*)(h + (size_t)s1 * 128) + lane);
      unsigned int v2 = *((const unsigned int*)(h + (size_t)s2 * 128) + lane);
      unsigned int v3 = *((const unsigned int*)(h + (size_t)s3 * 128) + lane);
      acc128(v0, c0, ax0, ay0); acc128(v1, c1, ax1, ay1);
      acc128(v2, c2, ax2, ay2); acc128(v3, c3, ax3, ay3);
    }
    for (; i < k; ++i) {
      int s = __shfl(me.x, i);
      float co = __int_as_float(__shfl(me.y, i));
      unsigned int v = *((const unsigned int*)(h + (size_t)s * 128) + lane);
      acc128(v, co, ax0, ay0);
    }
  }
  float ax = (ax0 + ax1) + (ax2 + ax3), ay = (ay0 + ay1) + (ay2 + ay3);
  *((unsigned int*)(out + (size_t)n * 128) + lane) =
      (unsigned int)f2bf(ax) | ((unsigned int)f2bf(ay) << 16);
}

// ---------------- bf16 MFMA GEMM + fused BN partial stats (R6 LDS version) ----------------
// C[Mpad,256] = A[Mpad,K] @ W[K,256]; 128x128 tile, BK=64, 4 waves 2x2.
// global_load_lds staging, XOR-pre-swizzled source + swizzled reads (conflict-free).
// Pad rows are zero -> no guards, exact-zero contribution to stats.

__global__ __launch_bounds__(256) void gemm_bf(const unsigned short* __restrict__ A,
                                               const unsigned short* __restrict__ Wt,
                                               unsigned short* __restrict__ C,
                                               int K,
                                               float* __restrict__ sums,
                                               float* __restrict__ sumsq) {
  __shared__ unsigned short As[128 * 64];
  __shared__ unsigned short Bs[128 * 64];
  int t = threadIdx.x;
  int w = t >> 6, lane = t & 63;
  int l16 = lane & 15, lhi = lane >> 4;
  int wr = w >> 1, wc = w & 1;
  int rowBase = blockIdx.x * 128, colBase = blockIdx.y * 128;
  f32x4 acc[4][4] = {};
  int srow = lane >> 3;   // 0..7 within 8-row segment
  int sg = lane & 7;      // 16B group within 128B row
  const unsigned short* Abase = A + (size_t)rowBase * K;
  const unsigned short* Bbase = Wt + (size_t)colBase * K;
  for (int k0 = 0; k0 < K; k0 += 64) {
#pragma unroll
    for (int i = 0; i < 4; ++i) {
      int rb = i * 32 + w * 8;          // segment base row (wave-uniform)
      int row = rb + srow;
      int gg = sg ^ (row & 7);          // pre-swizzled source group
      gload16(Abase + (size_t)row * K + k0 + gg * 8, &As[rb * 64]);
      gload16(Bbase + (size_t)row * K + k0 + gg * 8, &Bs[rb * 64]);
    }
    __syncthreads();
#pragma unroll
    for (int kk = 0; kk < 64; kk += 32) {
      int gb = (kk >> 3) + lhi;
      bf16x8 a[4], b[4];
#pragma unroll
      for (int i = 0; i < 4; ++i) {
        int ra = wr * 64 + i * 16 + l16;
        a[i] = *(const bf16x8*)&As[ra * 64 + ((gb ^ (ra & 7)) << 3)];
        int rb2 = wc * 64 + i * 16 + l16;
        b[i] = *(const bf16x8*)&Bs[rb2 * 64 + ((gb ^ (rb2 & 7)) << 3)];
      }
#pragma unroll
      for (int i = 0; i < 4; ++i)
#pragma unroll
        for (int j = 0; j < 4; ++j)
          acc[i][j] = __builtin_amdgcn_mfma_f32_16x16x32_bf16(a[i], b[j], acc[i][j], 0, 0, 0);
    }
    __syncthreads();
  }
#pragma unroll
  for (int i = 0; i < 4; ++i) {
#pragma unroll
    for (int rr = 0; rr < 4; ++rr) {
      int row = rowBase + wr * 64 + i * 16 + lhi * 4 + rr;
      size_t o = (size_t)row * 256 + colBase + wc * 64 + l16;
#pragma unroll
      for (int j = 0; j < 4; ++j) C[o + j * 16] = f2bf(acc[i][j][rr]);
    }
  }
#pragma unroll
  for (int j = 0; j < 4; ++j) {
    float s = 0.f, s2 = 0.f;
#pragma unroll
    for (int i = 0; i < 4; ++i)
#pragma unroll
      for (int rr = 0; rr < 4; ++rr) { float v = acc[i][j][rr]; s += v; s2 += v * v; }
    s  += __shfl_xor(s, 16);  s  += __shfl_xor(s, 32);
    s2 += __shfl_xor(s2, 16); s2 += __shfl_xor(s2, 32);
    if (lhi == 0) {
      int col = colBase + wc * 64 + j * 16 + l16;
      atomicAdd(&sums[col], s);
      atomicAdd(&sumsq[col], s2);
    }
  }
}

// ---------------- pool (BN2+ReLU fused, in-block finalize) + classifier ----------------

__global__ __launch_bounds__(256) void pool_final(const unsigned short* __restrict__ h,
                                                  const unsigned int* __restrict__ gstart,
                                                  const float* __restrict__ sums,
                                                  const float* __restrict__ sumsq,
                                                  const float* __restrict__ gamma,
                                                  const float* __restrict__ beta,
                                                  float invN,
                                                  const float* __restrict__ Wl,
                                                  const float* __restrict__ bl,
                                                  float* __restrict__ out, int NC) {
  __shared__ float s_sc[256], s_sh[256];
  __shared__ float4 part[4][64];
  __shared__ float p[256];
  int t = threadIdx.x, w = t >> 6, lane = t & 63;
  {
    float mean = sums[t] * invN;
    float var = sumsq[t] * invN - mean * mean;
    float scv = gamma[t] * rsqrtf(var + BN_EPS);
    s_sc[t] = scv;
    s_sh[t] = beta[t] - mean * scv;
  }
  __syncthreads();
  float4 sc = *(const float4*)&s_sc[lane * 4];
  float4 sh = *(const float4*)&s_sh[lane * 4];
  int g = blockIdx.x;
  int gs = (int)gstart[g], ge = (int)gstart[g + 1];
  float ax = 0.f, ay = 0.f, az = 0.f, aw = 0.f;
  for (int r = gs + w; r < ge; r += 4) {
    uint2 v = *((const uint2*)(h + (size_t)r * 256) + lane);
    ax += fmaxf(bf2f((unsigned short)(v.x & 0xffff)) * sc.x + sh.x, 0.f);
    ay += fmaxf(bf2f((unsigned short)(v.x >> 16)) * sc.y + sh.y, 0.f);
    az += fmaxf(bf2f((unsigned short)(v.y & 0xffff)) * sc.z + sh.z, 0.f);
    aw += fmaxf(bf2f((unsigned short)(v.y >> 16)) * sc.w + sh.w, 0.f);
  }
  part[w][lane] = make_float4(ax, ay, az, aw);
  __syncthreads();
  if (t < 64) {
    float inv = 1.0f / fmaxf((float)(ge - gs), 1.0f);
    float4 s0 = part[0][t], s1 = part[1][t], s2 = part[2][t], s3 = part[3][t];
    float4 r;
    r.x = (s0.x + s1.x + s2.x + s3.x) * inv;
    r.y = (s0.y + s1.y + s2.y + s3.y) * inv;
    r.z = (s0.z + s1.z + s2.z + s3.z) * inv;
    r.w = (s0.w + s1.w + s2.w + s3.w) * inv;
    *(float4*)&p[t * 4] = r;
  }
  __syncthreads();
  if (t < NC) {
    float s = bl[t];
    for (int k = 0; k < 256; ++k) s += p[k] * Wl[k * NC + t];
    out[g * NC + t] = s;
  }
}

// ---------------- launcher ----------------

extern "C" void kernel_launch(void* const* d_in, const int* in_sizes, int n_in,
                              void* d_out, int out_size, void* d_ws, size_t ws_size,
                              hipStream_t stream) {
  const float* x      = (const float*)d_in[0];
  const int*   ei     = (const int*)d_in[1];
  const int*   batch  = (const int*)d_in[2];
  const float* W0     = (const float*)d_in[3];
  const float* gamma0 = (const float*)d_in[5];
  const float* beta0  = (const float*)d_in[6];
  const float* W1     = (const float*)d_in[7];
  const float* gamma1 = (const float*)d_in[9];
  const float* beta1  = (const float*)d_in[10];
  const float* W2     = (const float*)d_in[11];
  const float* gamma2 = (const float*)d_in[13];
  const float* beta2  = (const float*)d_in[14];
  const float* Wl     = (const float*)d_in[15];
  const float* bl     = (const float*)d_in[16];
  float* out = (float*)d_out;

  int N = in_sizes[0] / 128;  // 50000
  int E = in_sizes[1] / 2;    // 800000
  int G = 128;
  int NC = 40;
  int Mpad = ((N + 127) / 128) * 128;  // 50048
  float invN = 1.0f / (float)N;
  const int* src = ei;
  const int* dst = ei + E;

  char* p = (char*)d_ws;
  auto alloc = [&](size_t bytes) -> void* {
    void* r = (void*)p;
    p += (bytes + 255) & ~(size_t)255;
    return r;
  };
  unsigned short* xb  = (unsigned short*)alloc((size_t)N * 128 * 2);
  unsigned short* hA  = (unsigned short*)alloc((size_t)Mpad * 256 * 2);
  unsigned short* hB  = (unsigned short*)alloc((size_t)Mpad * 256 * 2);
  unsigned short* Wt0 = (unsigned short*)alloc((size_t)256 * 128 * 2);
  unsigned short* Wt1 = (unsigned short*)alloc((size_t)256 * 256 * 2);
  unsigned short* Wt2 = (unsigned short*)alloc((size_t)256 * 256 * 2);
  int2*  csr      = (int2*) alloc((size_t)E * 8);
  int*   cc       = (int*)  alloc((size_t)(2 * N + 6 * 256) * 4);
  int*   counts   = cc;
  int*   cursor   = cc + N;
  float* stats    = (float*)(cc + 2 * N);
  float* sums0 = stats + 0 * 256, *sumsq0 = stats + 1 * 256;
  float* sums1 = stats + 2 * 256, *sumsq1 = stats + 3 * 256;
  float* sums2 = stats + 4 * 256, *sumsq2 = stats + 5 * 256;
  int*   offs     = (int*)  alloc((size_t)(N + 1) * 4);
  float* dinv     = (float*)alloc((size_t)N * 4);
  int*   blkSum   = (int*)  alloc(64 * 4);
  int*   blkOff   = (int*)  alloc(64 * 4);
  unsigned int* gstart = (unsigned int*)alloc((size_t)(G + 1) * 4);

  // ---- init ----
  hipMemsetAsync(cc, 0, (size_t)(2 * N + 6 * 256) * 4, stream);
  hipMemsetAsync(gstart, 0xFF, (size_t)(G + 1) * 4, stream);

  // ---- graph structure ----
  count_boundary<<<(E + 255) / 256, 256, 0, stream>>>(dst, E, counts, batch, N, gstart);
  int nb = (N + 1023) / 1024;
  scan1<<<nb, 256, 0, stream>>>(counts, N, offs, blkSum, dinv);
  scan2_fix<<<1, 64, 0, stream>>>(blkSum, nb, blkOff, offs, N, gstart, G);
  scan3<<<nb, 1024, 0, stream>>>(offs, N, blkOff);

  // ---- fill CSR + conversions + pad zeroing ----
  {
    int nx4 = N * 32;
    int npad128_8 = (Mpad - N) * 128 / 8;
    int npad256_8 = (Mpad - N) * 256 / 8;
    long long total = (long long)E + nx4 + 128 * 256 + 256 * 256 + 256 * 256
                    + npad128_8 + npad256_8;
    int blocks = (int)((total + 255) / 256);
    fill_cvt<<<blocks, 256, 0, stream>>>(src, dst, E, offs, cursor, dinv, csr,
                                         x, xb, nx4, W0, Wt0, W1, Wt1, W2, Wt2,
                                         hA + (size_t)N * 128, npad128_8,
                                         hA + (size_t)N * 256, npad256_8);
  }

  int aggBlocks = (N + 3) / 4;
  dim3 gemmGrid(Mpad / 128, 2);
  int bnBlocks = (N * 32 + 255) / 256;

  // ---- layer 0 ----
  agg128_bf<<<aggBlocks, 256, 0, stream>>>(xb, offs, csr, dinv, hA, N);
  gemm_bf<<<gemmGrid, 256, 0, stream>>>(hA, Wt0, hB, 128, sums0, sumsq0);
  bn_relu<<<bnBlocks, 256, 0, stream>>>(hB, sums0, sumsq0, gamma0, beta0, invN, N * 32);

  // ---- layer 1 ----
  agg256_bf<<<aggBlocks, 256, 0, stream>>>(hB, offs, csr, dinv, hA, N);
  gemm_bf<<<gemmGrid, 256, 0, stream>>>(hA, Wt1, hB, 256, sums1, sumsq1);
  bn_relu<<<bnBlocks, 256, 0, stream>>>(hB, sums1, sumsq1, gamma1, beta1, invN, N * 32);

  // ---- layer 2 ----
  agg256_bf<<<aggBlocks, 256, 0, stream>>>(hB, offs, csr, dinv, hA, N);
  gemm_bf<<<gemmGrid, 256, 0, stream>>>(hA, Wt2, hB, 256, sums2, sumsq2);

  // ---- pool (BN2 finalize in-block) + classifier ----
  pool_final<<<G, 256, 0, stream>>>(hB, gstart, sums2, sumsq2, gamma2, beta2, invN,
                                    Wl, bl, out, NC);
}

// Round 11
// 478.393 us; speedup vs baseline: 1.2058x; 1.0956x over previous
//
#include <hip/hip_runtime.h>

#define BN_EPS 1e-5f

typedef __attribute__((ext_vector_type(8))) short bf16x8;
typedef __attribute__((ext_vector_type(4))) float f32x4;

__device__ __forceinline__ float bf2f(unsigned short u) {
  return __uint_as_float(((unsigned int)u) << 16);
}
__device__ __forceinline__ unsigned short f2bf(float f) {
  unsigned int u = __float_as_uint(f);
  u = u + 0x7FFFu + ((u >> 16) & 1u);   // round-to-nearest-even
  return (unsigned short)(u >> 16);
}

// async global->LDS, 16B per lane; LDS dest = (wave-uniform base) + lane*16
__device__ __forceinline__ void gload16(const unsigned short* g, unsigned short* l) {
  __builtin_amdgcn_global_load_lds(
      (const __attribute__((address_space(1))) unsigned int*)g,
      (__attribute__((address_space(3))) unsigned int*)l, 16, 0, 0);
}

// ---------------- graph structure ----------------

__global__ __launch_bounds__(256) void count_boundary(const int* __restrict__ dst, int E,
                                                      int* __restrict__ counts,
                                                      const int* __restrict__ batch, int N,
                                                      unsigned int* __restrict__ gstart) {
  int e = blockIdx.x * 256 + threadIdx.x;
  if (e < E) atomicAdd(&counts[dst[e]], 1);
  if (e < N) {
    if (e == 0 || batch[e] != batch[e - 1]) atomicMin(&gstart[batch[e]], (unsigned int)e);
  }
}

__global__ __launch_bounds__(256) void scan1(const int* __restrict__ counts, int N,
                                             int* __restrict__ offs, int* __restrict__ blkSum,
                                             float* __restrict__ dinv) {
  __shared__ int sd[256];
  int t = threadIdx.x;
  int i0 = blockIdx.x * 1024 + t * 4;
  int v0 = (i0 + 0 < N) ? counts[i0 + 0] : 0;
  int v1 = (i0 + 1 < N) ? counts[i0 + 1] : 0;
  int v2 = (i0 + 2 < N) ? counts[i0 + 2] : 0;
  int v3 = (i0 + 3 < N) ? counts[i0 + 3] : 0;
  if (i0 + 0 < N) dinv[i0 + 0] = rsqrtf((float)(v0 + 1));
  if (i0 + 1 < N) dinv[i0 + 1] = rsqrtf((float)(v1 + 1));
  if (i0 + 2 < N) dinv[i0 + 2] = rsqrtf((float)(v2 + 1));
  if (i0 + 3 < N) dinv[i0 + 3] = rsqrtf((float)(v3 + 1));
  int tot = v0 + v1 + v2 + v3;
  sd[t] = tot;
  __syncthreads();
  for (int off = 1; off < 256; off <<= 1) {
    int x = (t >= off) ? sd[t - off] : 0;
    __syncthreads();
    sd[t] += x;
    __syncthreads();
  }
  int excl = sd[t] - tot;
  if (i0 + 0 < N) offs[i0 + 0] = excl;
  if (i0 + 1 < N) offs[i0 + 1] = excl + v0;
  if (i0 + 2 < N) offs[i0 + 2] = excl + v0 + v1;
  if (i0 + 3 < N) offs[i0 + 3] = excl + v0 + v1 + v2;
  if (t == 255) blkSum[blockIdx.x] = sd[255];
}

__global__ void scan2_fix(const int* __restrict__ blkSum, int nb, int* __restrict__ blkOff,
                          int* __restrict__ offs, int N,
                          unsigned int* __restrict__ gstart, int G) {
  if (blockIdx.x != 0) return;
  if (threadIdx.x == 0) {
    int run = 0;
    for (int b = 0; b < nb; ++b) { blkOff[b] = run; run += blkSum[b]; }
    offs[N] = run;
  } else if (threadIdx.x == 1) {
    gstart[G] = (unsigned int)N;
    for (int g = G - 1; g >= 0; --g)
      if (gstart[g] == 0xFFFFFFFFu) gstart[g] = gstart[g + 1];
  }
}

__global__ __launch_bounds__(1024) void scan3(int* __restrict__ offs, int N,
                                              const int* __restrict__ blkOff) {
  int i = blockIdx.x * 1024 + threadIdx.x;
  if (i < N) offs[i] += blkOff[blockIdx.x];
}

// ---------------- fill CSR + dtype conversions + pad zeroing (one dispatch) ----------------

__global__ __launch_bounds__(256) void fill_cvt(const int* __restrict__ src,
                                                const int* __restrict__ dst, int E,
                                                const int* __restrict__ offs,
                                                int* __restrict__ cursor,
                                                const float* __restrict__ dinv,
                                                int2* __restrict__ csr,
                                                const float* __restrict__ x,
                                                unsigned short* __restrict__ xb, int nx4,
                                                const float* __restrict__ W0,
                                                unsigned short* __restrict__ Wt0,
                                                const float* __restrict__ W1,
                                                unsigned short* __restrict__ Wt1,
                                                const float* __restrict__ W2,
                                                unsigned short* __restrict__ Wt2,
                                                unsigned short* __restrict__ pad128, int npad128_8,
                                                unsigned short* __restrict__ pad256, int npad256_8) {
  long long idx = (long long)blockIdx.x * 256 + threadIdx.x;
  if (idx < E) {
    int e = (int)idx;
    int s = src[e], d = dst[e];
    int pos = offs[d] + atomicAdd(&cursor[d], 1);
    csr[pos] = make_int2(s, __float_as_int(dinv[s] * dinv[d]));
    return;
  }
  idx -= E;
  if (idx < nx4) {
    float4 v = ((const float4*)x)[idx];
    unsigned int lo = (unsigned int)f2bf(v.x) | ((unsigned int)f2bf(v.y) << 16);
    unsigned int hi = (unsigned int)f2bf(v.z) | ((unsigned int)f2bf(v.w) << 16);
    ((uint2*)xb)[idx] = make_uint2(lo, hi);
    return;
  }
  idx -= nx4;
  if (idx < 128 * 256) {
    int k = (int)(idx >> 8), n = (int)(idx & 255);
    Wt0[n * 128 + k] = f2bf(W0[k * 256 + n]);
    return;
  }
  idx -= 128 * 256;
  if (idx < 256 * 256) {
    int k = (int)(idx >> 8), n = (int)(idx & 255);
    Wt1[n * 256 + k] = f2bf(W1[k * 256 + n]);
    return;
  }
  idx -= 256 * 256;
  if (idx < 256 * 256) {
    int k = (int)(idx >> 8), n = (int)(idx & 255);
    Wt2[n * 256 + k] = f2bf(W2[k * 256 + n]);
    return;
  }
  idx -= 256 * 256;
  if (idx < npad128_8) { ((uint4*)pad128)[idx] = make_uint4(0, 0, 0, 0); return; }
  idx -= npad128_8;
  if (idx < npad256_8) { ((uint4*)pad256)[idx] = make_uint4(0, 0, 0, 0); return; }
}

// ---------------- aggregation (gather, CSR by dst), one wave per node ----------------
// 8-edge unroll, 4 accumulator chains; BN scale/shift of the previous layer is
// computed in an LDS prologue and applied per gathered row (fused, R6-style).

__device__ __forceinline__ void acc256(uint2 v, float co, float4 sc, float4 sh,
                                       float& ax, float& ay, float& az, float& aw) {
  float fx = fmaxf(bf2f((unsigned short)(v.x & 0xffff)) * sc.x + sh.x, 0.f);
  float fy = fmaxf(bf2f((unsigned short)(v.x >> 16)) * sc.y + sh.y, 0.f);
  float fz = fmaxf(bf2f((unsigned short)(v.y & 0xffff)) * sc.z + sh.z, 0.f);
  float fw = fmaxf(bf2f((unsigned short)(v.y >> 16)) * sc.w + sh.w, 0.f);
  ax += co * fx; ay += co * fy; az += co * fz; aw += co * fw;
}

__global__ __launch_bounds__(256) void agg256_bf(const unsigned short* __restrict__ h,
                                                 const int* __restrict__ offs,
                                                 const int2* __restrict__ csr,
                                                 const float* __restrict__ dinv,
                                                 const float* __restrict__ sums,
                                                 const float* __restrict__ sumsq,
                                                 const float* __restrict__ gamma,
                                                 const float* __restrict__ beta,
                                                 float invN,
                                                 unsigned short* __restrict__ out, int N) {
  __shared__ float s_sc[256], s_sh[256];
  {
    int c = threadIdx.x;
    float mean = sums[c] * invN;
    float var = sumsq[c] * invN - mean * mean;
    float scv = gamma[c] * rsqrtf(var + BN_EPS);
    s_sc[c] = scv;
    s_sh[c] = beta[c] - mean * scv;
  }
  __syncthreads();
  int n = (blockIdx.x * 256 + threadIdx.x) >> 6;
  int lane = threadIdx.x & 63;
  if (n >= N) return;
  float4 sc = *(const float4*)&s_sc[lane * 4];
  float4 sh = *(const float4*)&s_sh[lane * 4];
  float di = dinv[n];
  float self = di * di;
  float ax0 = 0.f, ay0 = 0.f, az0 = 0.f, aw0 = 0.f;
  float ax1 = 0.f, ay1 = 0.f, az1 = 0.f, aw1 = 0.f;
  float ax2 = 0.f, ay2 = 0.f, az2 = 0.f, aw2 = 0.f;
  float ax3 = 0.f, ay3 = 0.f, az3 = 0.f, aw3 = 0.f;
  {
    uint2 v = *((const uint2*)(h + (size_t)n * 256) + lane);
    acc256(v, self, sc, sh, ax0, ay0, az0, aw0);
  }
  int e0 = offs[n], e1 = offs[n + 1];
  for (int eb = e0; eb < e1; eb += 64) {
    int k = min(64, e1 - eb);
    int2 me = make_int2(0, 0);
    if (lane < k) me = csr[eb + lane];
    int i = 0;
    for (; i + 8 <= k; i += 8) {
      int s0 = __shfl(me.x, i),     s1 = __shfl(me.x, i + 1);
      int s2 = __shfl(me.x, i + 2), s3 = __shfl(me.x, i + 3);
      int s4 = __shfl(me.x, i + 4), s5 = __shfl(me.x, i + 5);
      int s6 = __shfl(me.x, i + 6), s7 = __shfl(me.x, i + 7);
      float c0 = __int_as_float(__shfl(me.y, i));
      float c1 = __int_as_float(__shfl(me.y, i + 1));
      float c2 = __int_as_float(__shfl(me.y, i + 2));
      float c3 = __int_as_float(__shfl(me.y, i + 3));
      float c4 = __int_as_float(__shfl(me.y, i + 4));
      float c5 = __int_as_float(__shfl(me.y, i + 5));
      float c6 = __int_as_float(__shfl(me.y, i + 6));
      float c7 = __int_as_float(__shfl(me.y, i + 7));
      uint2 v0 = *((const uint2*)(h + (size_t)s0 * 256) + lane);
      uint2 v1 = *((const uint2*)(h + (size_t)s1 * 256) + lane);
      uint2 v2 = *((const uint2*)(h + (size_t)s2 * 256) + lane);
      uint2 v3 = *((const uint2*)(h + (size_t)s3 * 256) + lane);
      uint2 v4 = *((const uint2*)(h + (size_t)s4 * 256) + lane);
      uint2 v5 = *((const uint2*)(h + (size_t)s5 * 256) + lane);
      uint2 v6 = *((const uint2*)(h + (size_t)s6 * 256) + lane);
      uint2 v7 = *((const uint2*)(h + (size_t)s7 * 256) + lane);
      acc256(v0, c0, sc, sh, ax0, ay0, az0, aw0);
      acc256(v1, c1, sc, sh, ax1, ay1, az1, aw1);
      acc256(v2, c2, sc, sh, ax2, ay2, az2, aw2);
      acc256(v3, c3, sc, sh, ax3, ay3, az3, aw3);
      acc256(v4, c4, sc, sh, ax0, ay0, az0, aw0);
      acc256(v5, c5, sc, sh, ax1, ay1, az1, aw1);
      acc256(v6, c6, sc, sh, ax2, ay2, az2, aw2);
      acc256(v7, c7, sc, sh, ax3, ay3, az3, aw3);
    }
    for (; i + 4 <= k; i += 4) {
      int s0 = __shfl(me.x, i),     s1 = __shfl(me.x, i + 1);
      int s2 = __shfl(me.x, i + 2), s3 = __shfl(me.x, i + 3);
      float c0 = __int_as_float(__shfl(me.y, i));
      float c1 = __int_as_float(__shfl(me.y, i + 1));
      float c2 = __int_as_float(__shfl(me.y, i + 2));
      float c3 = __int_as_float(__shfl(me.y, i + 3));
      uint2 v0 = *((const uint2*)(h + (size_t)s0 * 256) + lane);
      uint2 v1 = *((const uint2*)(h + (size_t)s1 * 256) + lane);
      uint2 v2 = *((const uint2*)(h + (size_t)s2 * 256) + lane);
      uint2 v3 = *((const uint2*)(h + (size_t)s3 * 256) + lane);
      acc256(v0, c0, sc, sh, ax0, ay0, az0, aw0);
      acc256(v1, c1, sc, sh, ax1, ay1, az1, aw1);
      acc256(v2, c2, sc, sh, ax2, ay2, az2, aw2);
      acc256(v3, c3, sc, sh, ax3, ay3, az3, aw3);
    }
    for (; i < k; ++i) {
      int s = __shfl(me.x, i);
      float co = __int_as_float(__shfl(me.y, i));
      uint2 v = *((const uint2*)(h + (size_t)s * 256) + lane);
      acc256(v, co, sc, sh, ax0, ay0, az0, aw0);
    }
  }
  float ax = (ax0 + ax1) + (ax2 + ax3), ay = (ay0 + ay1) + (ay2 + ay3);
  float az = (az0 + az1) + (az2 + az3), aw = (aw0 + aw1) + (aw2 + aw3);
  unsigned int lo = (unsigned int)f2bf(ax) | ((unsigned int)f2bf(ay) << 16);
  unsigned int hi = (unsigned int)f2bf(az) | ((unsigned int)f2bf(aw) << 16);
  *((uint2*)(out + (size_t)n * 256) + lane) = make_uint2(lo, hi);
}

__device__ __forceinline__ void acc128(unsigned int v, float co, float& ax, float& ay) {
  ax += co * bf2f((unsigned short)(v & 0xffff));
  ay += co * bf2f((unsigned short)(v >> 16));
}

__global__ __launch_bounds__(256) void agg128_bf(const unsigned short* __restrict__ h,
                                                 const int* __restrict__ offs,
                                                 const int2* __restrict__ csr,
                                                 const float* __restrict__ dinv,
                                                 unsigned short* __restrict__ out, int N) {
  int n = (blockIdx.x * 256 + threadIdx.x) >> 6;
  int lane = threadIdx.x & 63;
  if (n >= N) return;
  float di = dinv[n];
  float self = di * di;
  float ax0 = 0.f, ay0 = 0.f, ax1 = 0.f, ay1 = 0.f;
  float ax2 = 0.f, ay2 = 0.f, ax3 = 0.f, ay3 = 0.f;
  {
    unsigned int v = *((const unsigned int*)(h + (size_t)n * 128) + lane);
    acc128(v, self, ax0, ay0);
  }
  int e0 = offs[n], e1 = offs[n + 1];
  for (int eb = e0; eb < e1; eb += 64) {
    int k = min(64, e1 - eb);
    int2 me = make_int2(0, 0);
    if (lane < k) me = csr[eb + lane];
    int i = 0;
    for (; i + 8 <= k; i += 8) {
      int s0 = __shfl(me.x, i),     s1 = __shfl(me.x, i + 1);
      int s2 = __shfl(me.x, i + 2), s3 = __shfl(me.x, i + 3);
      int s4 = __shfl(me.x, i + 4), s5 = __shfl(me.x, i + 5);
      int s6 = __shfl(me.x, i + 6), s7 = __shfl(me.x, i + 7);
      float c0 = __int_as_float(__shfl(me.y, i));
      float c1 = __int_as_float(__shfl(me.y, i + 1));
      float c2 = __int_as_float(__shfl(me.y, i + 2));
      float c3 = __int_as_float(__shfl(me.y, i + 3));
      float c4 = __int_as_float(__shfl(me.y, i + 4));
      float c5 = __int_as_float(__shfl(me.y, i + 5));
      float c6 = __int_as_float(__shfl(me.y, i + 6));
      float c7 = __int_as_float(__shfl(me.y, i + 7));
      unsigned int v0 = *((const unsigned int*)(h + (size_t)s0 * 128) + lane);
      unsigned int v1 = *((const unsigned int*)(h + (size_t)s1 * 128) + lane);
      unsigned int v2 = *((const unsigned int*)(h + (size_t)s2 * 128) + lane);
      unsigned int v3 = *((const unsigned int*)(h + (size_t)s3 * 128) + lane);
      unsigned int v4 = *((const unsigned int*)(h + (size_t)s4 * 128) + lane);
      unsigned int v5 = *((const unsigned int*)(h + (size_t)s5 * 128) + lane);
      unsigned int v6 = *((const unsigned int*)(h + (size_t)s6 * 128) + lane);
      unsigned int v7 = *((const unsigned int*)(h + (size_t)s7 * 128) + lane);
      acc128(v0, c0, ax0, ay0); acc128(v1, c1, ax1, ay1);
      acc128(v2, c2, ax2, ay2); acc128(v3, c3, ax3, ay3);
      acc128(v4, c4, ax0, ay0); acc128(v5, c5, ax1, ay1);
      acc128(v6, c6, ax2, ay2); acc128(v7, c7, ax3, ay3);
    }
    for (; i + 4 <= k; i += 4) {
      int s0 = __shfl(me.x, i),     s1 = __shfl(me.x, i + 1);
      int s2 = __shfl(me.x, i + 2), s3 = __shfl(me.x, i + 3);
      float c0 = __int_as_float(__shfl(me.y, i));
      float c1 = __int_as_float(__shfl(me.y, i + 1));
      float c2 = __int_as_float(__shfl(me.y, i + 2));
      float c3 = __int_as_float(__shfl(me.y, i + 3));
      unsigned int v0 = *((const unsigned int*)(h + (size_t)s0 * 128) + lane);
      unsigned int v1 = *((const unsigned int*)(h + (size_t)s1 * 128) + lane);
      unsigned int v2 = *((const unsigned int*)(h + (size_t)s2 * 128) + lane);
      unsigned int v3 = *((const unsigned int*)(h + (size_t)s3 * 128) + lane);
      acc128(v0, c0, ax0, ay0); acc128(v1, c1, ax1, ay1);
      acc128(v2, c2, ax2, ay2); acc128(v3, c3, ax3, ay3);
    }
    for (; i < k; ++i) {
      int s = __shfl(me.x, i);
      float co = __int_as_float(__shfl(me.y, i));
      unsigned int v = *((const unsigned int*)(h + (size_t)s * 128) + lane);
      acc128(v, co, ax0, ay0);
    }
  }
  float ax = (ax0 + ax1) + (ax2 + ax3), ay = (ay0 + ay1) + (ay2 + ay3);
  *((unsigned int*)(out + (size_t)n * 128) + lane) =
      (unsigned int)f2bf(ax) | ((unsigned int)f2bf(ay) << 16);
}

// ---------------- bf16 MFMA GEMM + fused BN partial stats ----------------
// C[Mpad,256] = A[Mpad,K] @ W[K,256]; FULL-WIDTH tile 128x256, BK=64,
// 512 threads = 8 waves in 2 (row) x 4 (col) quadrants of 64x64 each.
// A is staged ONCE per row-tile (was twice with the 2-col-half grid).
// global_load_lds staging with XOR-pre-swizzled source + swizzled reads.
// Pad rows are zero -> no guards, exact-zero contribution to stats.

__global__ __launch_bounds__(512) void gemm_bf(const unsigned short* __restrict__ A,
                                               const unsigned short* __restrict__ Wt,
                                               unsigned short* __restrict__ C,
                                               int K,
                                               float* __restrict__ sums,
                                               float* __restrict__ sumsq) {
  __shared__ unsigned short As[128 * 64];   // 16 KB
  __shared__ unsigned short Bs[256 * 64];   // 32 KB
  int t = threadIdx.x;
  int w = t >> 6, lane = t & 63;
  int l16 = lane & 15, lhi = lane >> 4;
  int wr = w >> 2, wc = w & 3;              // 2x4 quadrants, each 64 rows x 64 cols
  int rowBase = blockIdx.x * 128;
  f32x4 acc[4][4] = {};
  int srow = lane >> 3;   // 0..7 within 8-row segment
  int sg = lane & 7;      // 16B group within 128B row
  const unsigned short* Abase = A + (size_t)rowBase * K;
  for (int k0 = 0; k0 < K; k0 += 64) {
    // A: 128 rows in 2 rounds of (8 waves x 8 rows)
#pragma unroll
    for (int r2 = 0; r2 < 2; ++r2) {
      int rb = r2 * 64 + w * 8;
      int row = rb + srow;
      int gg = sg ^ (row & 7);
      gload16(Abase + (size_t)row * K + k0 + gg * 8, &As[rb * 64]);
    }
    // B: 256 rows in 4 rounds
#pragma unroll
    for (int r4 = 0; r4 < 4; ++r4) {
      int rb = r4 * 64 + w * 8;
      int row = rb + srow;
      int gg = sg ^ (row & 7);
      gload16(Wt + (size_t)row * K + k0 + gg * 8, &Bs[rb * 64]);
    }
    __syncthreads();
#pragma unroll
    for (int kk = 0; kk < 64; kk += 32) {
      int gb = (kk >> 3) + lhi;
      bf16x8 a[4], b[4];
#pragma unroll
      for (int i = 0; i < 4; ++i) {
        int ra = wr * 64 + i * 16 + l16;
        a[i] = *(const bf16x8*)&As[ra * 64 + ((gb ^ (ra & 7)) << 3)];
        int rb2 = wc * 64 + i * 16 + l16;
        b[i] = *(const bf16x8*)&Bs[rb2 * 64 + ((gb ^ (rb2 & 7)) << 3)];
      }
#pragma unroll
      for (int i = 0; i < 4; ++i)
#pragma unroll
        for (int j = 0; j < 4; ++j)
          acc[i][j] = __builtin_amdgcn_mfma_f32_16x16x32_bf16(a[i], b[j], acc[i][j], 0, 0, 0);
    }
    __syncthreads();
  }
  // C write: row = rowBase + wr*64 + i*16 + lhi*4 + rr; col = wc*64 + j*16 + l16
#pragma unroll
  for (int i = 0; i < 4; ++i) {
#pragma unroll
    for (int rr = 0; rr < 4; ++rr) {
      int row = rowBase + wr * 64 + i * 16 + lhi * 4 + rr;
      size_t o = (size_t)row * 256 + wc * 64 + l16;
#pragma unroll
      for (int j = 0; j < 4; ++j) C[o + j * 16] = f2bf(acc[i][j][rr]);
    }
  }
  // fused BN partial stats (pad rows contribute exact zeros)
#pragma unroll
  for (int j = 0; j < 4; ++j) {
    float s = 0.f, s2 = 0.f;
#pragma unroll
    for (int i = 0; i < 4; ++i)
#pragma unroll
      for (int rr = 0; rr < 4; ++rr) { float v = acc[i][j][rr]; s += v; s2 += v * v; }
    s  += __shfl_xor(s, 16);  s  += __shfl_xor(s, 32);
    s2 += __shfl_xor(s2, 16); s2 += __shfl_xor(s2, 32);
    if (lhi == 0) {
      int col = wc * 64 + j * 16 + l16;
      atomicAdd(&sums[col], s);
      atomicAdd(&sumsq[col], s2);
    }
  }
}

// ---------------- pool (BN2+ReLU fused, in-block finalize) + classifier ----------------

__global__ __launch_bounds__(256) void pool_final(const unsigned short* __restrict__ h,
                                                  const unsigned int* __restrict__ gstart,
                                                  const float* __restrict__ sums,
                                                  const float* __restrict__ sumsq,
                                                  const float* __restrict__ gamma,
                                                  const float* __restrict__ beta,
                                                  float invN,
                                                  const float* __restrict__ Wl,
                                                  const float* __restrict__ bl,
                                                  float* __restrict__ out, int NC) {
  __shared__ float s_sc[256], s_sh[256];
  __shared__ float4 part[4][64];
  __shared__ float p[256];
  int t = threadIdx.x, w = t >> 6, lane = t & 63;
  {
    float mean = sums[t] * invN;
    float var = sumsq[t] * invN - mean * mean;
    float scv = gamma[t] * rsqrtf(var + BN_EPS);
    s_sc[t] = scv;
    s_sh[t] = beta[t] - mean * scv;
  }
  __syncthreads();
  float4 sc = *(const float4*)&s_sc[lane * 4];
  float4 sh = *(const float4*)&s_sh[lane * 4];
  int g = blockIdx.x;
  int gs = (int)gstart[g], ge = (int)gstart[g + 1];
  float ax = 0.f, ay = 0.f, az = 0.f, aw = 0.f;
  for (int r = gs + w; r < ge; r += 4) {
    uint2 v = *((const uint2*)(h + (size_t)r * 256) + lane);
    ax += fmaxf(bf2f((unsigned short)(v.x & 0xffff)) * sc.x + sh.x, 0.f);
    ay += fmaxf(bf2f((unsigned short)(v.x >> 16)) * sc.y + sh.y, 0.f);
    az += fmaxf(bf2f((unsigned short)(v.y & 0xffff)) * sc.z + sh.z, 0.f);
    aw += fmaxf(bf2f((unsigned short)(v.y >> 16)) * sc.w + sh.w, 0.f);
  }
  part[w][lane] = make_float4(ax, ay, az, aw);
  __syncthreads();
  if (t < 64) {
    float inv = 1.0f / fmaxf((float)(ge - gs), 1.0f);
    float4 s0 = part[0][t], s1 = part[1][t], s2 = part[2][t], s3 = part[3][t];
    float4 r;
    r.x = (s0.x + s1.x + s2.x + s3.x) * inv;
    r.y = (s0.y + s1.y + s2.y + s3.y) * inv;
    r.z = (s0.z + s1.z + s2.z + s3.z) * inv;
    r.w = (s0.w + s1.w + s2.w + s3.w) * inv;
    *(float4*)&p[t * 4] = r;
  }
  __syncthreads();
  if (t < NC) {
    float s = bl[t];
    for (int k = 0; k < 256; ++k) s += p[k] * Wl[k * NC + t];
    out[g * NC + t] = s;
  }
}

// ---------------- launcher ----------------

extern "C" void kernel_launch(void* const* d_in, const int* in_sizes, int n_in,
                              void* d_out, int out_size, void* d_ws, size_t ws_size,
                              hipStream_t stream) {
  const float* x      = (const float*)d_in[0];
  const int*   ei     = (const int*)d_in[1];
  const int*   batch  = (const int*)d_in[2];
  const float* W0     = (const float*)d_in[3];
  const float* gamma0 = (const float*)d_in[5];
  const float* beta0  = (const float*)d_in[6];
  const float* W1     = (const float*)d_in[7];
  const float* gamma1 = (const float*)d_in[9];
  const float* beta1  = (const float*)d_in[10];
  const float* W2     = (const float*)d_in[11];
  const float* gamma2 = (const float*)d_in[13];
  const float* beta2  = (const float*)d_in[14];
  const float* Wl     = (const float*)d_in[15];
  const float* bl     = (const float*)d_in[16];
  float* out = (float*)d_out;

  int N = in_sizes[0] / 128;  // 50000
  int E = in_sizes[1] / 2;    // 800000
  int G = 128;
  int NC = 40;
  int Mpad = ((N + 127) / 128) * 128;  // 50048
  float invN = 1.0f / (float)N;
  const int* src = ei;
  const int* dst = ei + E;

  char* p = (char*)d_ws;
  auto alloc = [&](size_t bytes) -> void* {
    void* r = (void*)p;
    p += (bytes + 255) & ~(size_t)255;
    return r;
  };
  unsigned short* xb  = (unsigned short*)alloc((size_t)N * 128 * 2);
  unsigned short* hA  = (unsigned short*)alloc((size_t)Mpad * 256 * 2);
  unsigned short* hB  = (unsigned short*)alloc((size_t)Mpad * 256 * 2);
  unsigned short* Wt0 = (unsigned short*)alloc((size_t)256 * 128 * 2);
  unsigned short* Wt1 = (unsigned short*)alloc((size_t)256 * 256 * 2);
  unsigned short* Wt2 = (unsigned short*)alloc((size_t)256 * 256 * 2);
  int2*  csr      = (int2*) alloc((size_t)E * 8);
  int*   cc       = (int*)  alloc((size_t)(2 * N + 6 * 256) * 4);
  int*   counts   = cc;
  int*   cursor   = cc + N;
  float* stats    = (float*)(cc + 2 * N);
  float* sums0 = stats + 0 * 256, *sumsq0 = stats + 1 * 256;
  float* sums1 = stats + 2 * 256, *sumsq1 = stats + 3 * 256;
  float* sums2 = stats + 4 * 256, *sumsq2 = stats + 5 * 256;
  int*   offs     = (int*)  alloc((size_t)(N + 1) * 4);
  float* dinv     = (float*)alloc((size_t)N * 4);
  int*   blkSum   = (int*)  alloc(64 * 4);
  int*   blkOff   = (int*)  alloc(64 * 4);
  unsigned int* gstart = (unsigned int*)alloc((size_t)(G + 1) * 4);

  // ---- init ----
  hipMemsetAsync(cc, 0, (size_t)(2 * N + 6 * 256) * 4, stream);
  hipMemsetAsync(gstart, 0xFF, (size_t)(G + 1) * 4, stream);

  // ---- graph structure ----
  count_boundary<<<(E + 255) / 256, 256, 0, stream>>>(dst, E, counts, batch, N, gstart);
  int nb = (N + 1023) / 1024;
  scan1<<<nb, 256, 0, stream>>>(counts, N, offs, blkSum, dinv);
  scan2_fix<<<1, 64, 0, stream>>>(blkSum, nb, blkOff, offs, N, gstart, G);
  scan3<<<nb, 1024, 0, stream>>>(offs, N, blkOff);

  // ---- fill CSR + conversions + pad zeroing ----
  {
    int nx4 = N * 32;
    int npad128_8 = (Mpad - N) * 128 / 8;
    int npad256_8 = (Mpad - N) * 256 / 8;
    long long total = (long long)E + nx4 + 128 * 256 + 256 * 256 + 256 * 256
                    + npad128_8 + npad256_8;
    int blocks = (int)((total + 255) / 256);
    fill_cvt<<<blocks, 256, 0, stream>>>(src, dst, E, offs, cursor, dinv, csr,
                                         x, xb, nx4, W0, Wt0, W1, Wt1, W2, Wt2,
                                         hA + (size_t)N * 128, npad128_8,
                                         hA + (size_t)N * 256, npad256_8);
  }

  int aggBlocks = (N + 3) / 4;
  int gemmBlocks = Mpad / 128;  // 391

  // ---- layer 0 ----
  agg128_bf<<<aggBlocks, 256, 0, stream>>>(xb, offs, csr, dinv, hA, N);
  gemm_bf<<<gemmBlocks, 512, 0, stream>>>(hA, Wt0, hB, 128, sums0, sumsq0);

  // ---- layer 1 (BN0 finalize + ReLU fused into gather prologue) ----
  agg256_bf<<<aggBlocks, 256, 0, stream>>>(hB, offs, csr, dinv, sums0, sumsq0,
                                           gamma0, beta0, invN, hA, N);
  gemm_bf<<<gemmBlocks, 512, 0, stream>>>(hA, Wt1, hB, 256, sums1, sumsq1);

  // ---- layer 2 ----
  agg256_bf<<<aggBlocks, 256, 0, stream>>>(hB, offs, csr, dinv, sums1, sumsq1,
                                           gamma1, beta1, invN, hA, N);
  gemm_bf<<<gemmBlocks, 512, 0, stream>>>(hA, Wt2, hB, 256, sums2, sumsq2);

  // ---- pool (BN2 finalize in-block) + classifier ----
  pool_final<<<G, 256, 0, stream>>>(hB, gstart, sums2, sumsq2, gamma2, beta2, invN,
                                    Wl, bl, out, NC);
}